// Round 4
// baseline (1867.506 us; speedup 1.0000x reference)
//
#include <hip/hip_runtime.h>

#define NHID    1024
#define BATCH   128
#define LSTEPS  1000
#define DTC     0.042f
#define THETA   1.0f
#define TAUM    20.0f

#define RL(VS,I)  ((unsigned)__builtin_amdgcn_readlane((VS),(I)))

// Sum rows of `mat` (byte-offset list) into acc, at column h. Offsets for
// k<256 come from lane-held registers v0..v3 (readlane -> SGPR -> saddr
// loads); k>=256 falls back to the LDS list (rare). Two-stage pipeline:
// chunk k+1's loads issue before chunk k's adds. Accumulation order is
// strictly ascending k -> numerically identical to the R1/R3 kernels.
__device__ __forceinline__ float gather_rows(float acc, const char* mat, int h,
                                             const unsigned* __restrict__ Lds,
                                             int v0, int v1, int v2, int v3, int n)
{
    if (n <= 0) return acc;
    const int nf = (n < 256) ? n : 256;
    const int M  = (nf + 7) & ~7;
    float c0,c1,c2,c3,c4,c5,c6,c7;
    {
        const unsigned q0=RL(v0,0),q1=RL(v0,1),q2=RL(v0,2),q3=RL(v0,3),
                       q4=RL(v0,4),q5=RL(v0,5),q6=RL(v0,6),q7=RL(v0,7);
        c0=((const float*)(mat+q0))[h]; c1=((const float*)(mat+q1))[h];
        c2=((const float*)(mat+q2))[h]; c3=((const float*)(mat+q3))[h];
        c4=((const float*)(mat+q4))[h]; c5=((const float*)(mat+q5))[h];
        c6=((const float*)(mat+q6))[h]; c7=((const float*)(mat+q7))[h];
    }
    int k = 8;
    #pragma unroll 1
    for (; k < M; k += 8) {
        const int vs = (k < 64) ? v0 : (k < 128) ? v1 : (k < 192) ? v2 : v3;
        const int kb = k & 63;
        const unsigned t0=RL(vs,kb+0),t1=RL(vs,kb+1),t2=RL(vs,kb+2),t3=RL(vs,kb+3),
                       t4=RL(vs,kb+4),t5=RL(vs,kb+5),t6=RL(vs,kb+6),t7=RL(vs,kb+7);
        const float d0=((const float*)(mat+t0))[h], d1=((const float*)(mat+t1))[h],
                    d2=((const float*)(mat+t2))[h], d3=((const float*)(mat+t3))[h],
                    d4=((const float*)(mat+t4))[h], d5=((const float*)(mat+t5))[h],
                    d6=((const float*)(mat+t6))[h], d7=((const float*)(mat+t7))[h];
        acc += c0; acc += c1; acc += c2; acc += c3;
        acc += c4; acc += c5; acc += c6; acc += c7;
        c0=d0; c1=d1; c2=d2; c3=d3; c4=d4; c5=d5; c6=d6; c7=d7;
    }
    const int base = k - 8;
    acc += c0;
    acc += (base+1 < nf) ? c1 : 0.0f;
    acc += (base+2 < nf) ? c2 : 0.0f;
    acc += (base+3 < nf) ? c3 : 0.0f;
    acc += (base+4 < nf) ? c4 : 0.0f;
    acc += (base+5 < nf) ? c5 : 0.0f;
    acc += (base+6 < nf) ? c6 : 0.0f;
    acc += (base+7 < nf) ? c7 : 0.0f;
    for (int kk = 256; kk < n; ++kk)                 // correctness fallback
        acc += ((const float*)(mat + Lds[kk]))[h];
    return acc;
}

__global__ __launch_bounds__(1024) void coesn_sim(
    const float* __restrict__ x,        // (B, L, 1)
    const float* __restrict__ x2h,      // (1, H)
    const float* __restrict__ h2h,      // (H, H)
    const float* __restrict__ bias,     // (H)
    const float* __restrict__ lif2hrf,  // (H, H)
    const float* __restrict__ gamma_,   // (H)
    const float* __restrict__ eps_,     // (H)
    float* __restrict__ out,            // (B, 3H) features
    unsigned int* __restrict__ ws)      // (B, 2) spike counts
{
    const int b    = blockIdx.x;
    const int h    = threadIdx.x;
    const int wv   = h >> 6;
    const int lane = h & 63;
    const int wvs  = __builtin_amdgcn_readfirstlane(wv);

    __shared__ unsigned int Ls[1024];   // HRF spike row byte-offsets
    __shared__ unsigned int Ll[1024];   // LIF spike row byte-offsets
    __shared__ int Cs[16], Cl[16];
    __shared__ unsigned int red[16];

    Ls[h] = 0; Ll[h] = 0;               // keep stale entries in-range forever
    if (h < 16) { Cs[h] = 0; Cl[h] = 0; }

    float hy = 0.f, hz = 0.f, v = 0.f, rp = 0.f;
    float hysum = 0.f, hysq = 0.f;
    unsigned int chrf = 0, clif = 0;

    const float g    = gamma_[h];
    const float e    = eps_[h];
    const float bi   = bias[h];
    const float win  = x2h[h];
    const float ref_decay = expf((float)(-0.042 / 0.25));
    const float* xb  = x + (size_t)b * LSTEPS;

    const char* hmat = (const char*)h2h;
    const char* lmat = (const char*)lif2hrf;

    const unsigned long long below = (1ULL << lane) - 1ULL;

    int ns = 0;   // HRF list length (phase A bound); 0 at t=0

    __syncthreads();

    for (int t = 0; t < LSTEPS; ++t) {
        // ---- phase A: cur = x*x2h + bias + sum of spiking h2h rows ----
        const int s0 = (int)Ls[lane];
        const int s1 = (int)Ls[64 + lane];
        const int s2 = (int)Ls[128 + lane];
        const int s3 = (int)Ls[192 + lane];
        const float xv = xb[t];
        const float cur = gather_rows(xv * win + bi, hmat, h, Ls, s0, s1, s2, s3, ns);

        // ---- phase B: LIF update + spike + list build ----
        v = v + DTC * (-v / TAUM + cur);
        const float lsp = (v > THETA) ? 1.f : 0.f;
        v -= lsp * THETA;
        clif += (unsigned)lsp;
        const unsigned long long balL = __ballot(lsp > 0.5f);
        if (lane == 0) Cl[wv] = (int)__popcll(balL);
        __syncthreads();
        int cv = Cl[lane & 15];
        int pre = 0, nl = 0;
        #pragma unroll
        for (int i = 0; i < 16; ++i) {
            const int ci = __builtin_amdgcn_readlane(cv, i);
            nl += ci;
            pre += (i < wvs) ? ci : 0;
        }
        if (lsp > 0.5f) Ll[pre + (int)__popcll(balL & below)] = (unsigned)(h * 4096);
        __syncthreads();

        // ---- phase C: drive = sum of spiking lif2hrf rows ----
        const int l0 = (int)Ll[lane];
        const int l1 = (int)Ll[64 + lane];
        const int l2 = (int)Ll[128 + lane];
        const int l3 = (int)Ll[192 + lane];
        const float dr = gather_rows(0.0f, lmat, h, Ll, l0, l1, l2, l3, nl);

        // ---- phase D: HRF update + spike + stats + list build ----
        hz = hz + DTC * (dr - g * hy - e * hz);
        hy = hy + DTC * hz;
        const float sn = ((hy - THETA - rp) > 0.f) ? 1.f : 0.f;
        rp = rp * ref_decay + sn;
        hysum += hy;
        hysq  += hy * hy;
        chrf += (unsigned)sn;
        const unsigned long long balS = __ballot(sn > 0.5f);
        if (lane == 0) Cs[wv] = (int)__popcll(balS);
        __syncthreads();
        cv = Cs[lane & 15];
        pre = 0; ns = 0;
        #pragma unroll
        for (int i = 0; i < 16; ++i) {
            const int ci = __builtin_amdgcn_readlane(cv, i);
            ns += ci;
            pre += (i < wvs) ? ci : 0;
        }
        if (sn > 0.5f) Ls[pre + (int)__popcll(balS & below)] = (unsigned)(h * 4096);
        __syncthreads();
    }

    // ---- epilogue: features ----
    const float Lf   = (float)LSTEPS;
    const float mean = hysum / Lf;
    const float rms  = sqrtf(hysq / Lf + 1e-8f);
    float var = hysq / Lf - mean * mean;
    var = fmaxf(var, 1e-8f);
    float* ob = out + (size_t)b * (3 * NHID);
    ob[h]            = rms;
    ob[NHID + h]     = sqrtf(var);
    ob[2 * NHID + h] = hy;

    // ---- spike-count reduction (exact ints) ----
    unsigned int c = chrf;
    for (int off = 32; off > 0; off >>= 1) c += __shfl_down(c, off, 64);
    if (lane == 0) red[wv] = c;
    __syncthreads();
    if (h == 0) {
        unsigned int tot = 0;
        for (int i = 0; i < 16; ++i) tot += red[i];
        ws[b * 2] = tot;
    }
    __syncthreads();
    c = clif;
    for (int off = 32; off > 0; off >>= 1) c += __shfl_down(c, off, 64);
    if (lane == 0) red[wv] = c;
    __syncthreads();
    if (h == 0) {
        unsigned int tot = 0;
        for (int i = 0; i < 16; ++i) tot += red[i];
        ws[b * 2 + 1] = tot;
    }
}

__global__ void coesn_final(const unsigned int* __restrict__ ws,
                            float* __restrict__ out)
{
    if (threadIdx.x == 0 && blockIdx.x == 0) {
        unsigned long long hrf = 0, lif = 0;
        for (int b = 0; b < BATCH; ++b) {
            hrf += ws[b * 2];
            lif += ws[b * 2 + 1];
        }
        const float denom = (float)BATCH * (float)LSTEPS * (float)NHID;
        const float r_hrf = (float)hrf / denom;
        const float r_lif = (float)lif / denom;
        float* s = out + (size_t)BATCH * 3 * NHID;
        s[0] = r_hrf;
        s[1] = r_hrf;
        s[2] = r_lif;
    }
}

extern "C" void kernel_launch(void* const* d_in, const int* in_sizes, int n_in,
                              void* d_out, int out_size, void* d_ws, size_t ws_size,
                              hipStream_t stream) {
    const float* x       = (const float*)d_in[0];
    const float* x2h     = (const float*)d_in[1];
    const float* h2h     = (const float*)d_in[2];
    const float* bias    = (const float*)d_in[3];
    const float* lif2hrf = (const float*)d_in[4];
    const float* gamma_  = (const float*)d_in[5];
    const float* eps_    = (const float*)d_in[6];
    float* out = (float*)d_out;
    unsigned int* wsp = (unsigned int*)d_ws;

    coesn_sim<<<BATCH, NHID, 0, stream>>>(x, x2h, h2h, bias, lif2hrf, gamma_, eps_, out, wsp);
    coesn_final<<<1, 64, 0, stream>>>(wsp, out);
}

// Round 5
// 1742.695 us; speedup vs baseline: 1.0716x; 1.0716x over previous
//
#include <hip/hip_runtime.h>

#define NHID    1024
#define BATCH   128
#define LSTEPS  1000
#define DTC     0.042f
#define THETA   1.0f
#define TAUM    20.0f
#define LISTCAP 1032          // 1024 + pad so fixed-width reads stay in-range

// Fixed-size gather: ROWS offset ds_reads issue together, then ROWS global
// loads issue together (32-bit voffset off+4h against uniform base -> saddr
// form), then ROWS adds (last 8 predicated). One lgkmcnt + one vmcnt wait
// per call instead of one per 8-row chunk. n is block-uniform; stale list
// entries past n are valid in-range offsets (list zero-init'd), so the
// speculative loads are safe and the predicated adds keep exact numerics.
template<int ROWS>
__device__ __forceinline__ float gather_fixed(float acc, const char* __restrict__ mat,
                                              unsigned h4,
                                              const unsigned* __restrict__ L, int n)
{
    unsigned off[ROWS];
    #pragma unroll
    for (int k = 0; k < ROWS; ++k) off[k] = L[k];
    float val[ROWS];
    #pragma unroll
    for (int k = 0; k < ROWS; ++k)
        val[k] = *(const float*)(mat + (size_t)(off[k] + h4));
    #pragma unroll
    for (int k = 0; k < ROWS; ++k) {
        if (k < ROWS - 8) acc += val[k];          // statically guaranteed k < n
        else              acc += (k < n) ? val[k] : 0.0f;
    }
    return acc;
}

__device__ __forceinline__ float gather_rows(float acc, const char* __restrict__ mat,
                                             unsigned h4,
                                             const unsigned* __restrict__ L, int n)
{
    if (n <= 0)  return acc;
    if (n <= 8)  return gather_fixed<8 >(acc, mat, h4, L, n);
    if (n <= 16) return gather_fixed<16>(acc, mat, h4, L, n);
    if (n <= 24) return gather_fixed<24>(acc, mat, h4, L, n);
    if (n <= 32) return gather_fixed<32>(acc, mat, h4, L, n);
    // n > 32: 32 unconditional rows, then rolled 8-chunks with predicated tail
    {
        unsigned off[32];
        #pragma unroll
        for (int i = 0; i < 32; ++i) off[i] = L[i];
        float val[32];
        #pragma unroll
        for (int i = 0; i < 32; ++i) val[i] = *(const float*)(mat + (size_t)(off[i] + h4));
        #pragma unroll
        for (int i = 0; i < 32; ++i) acc += val[i];
    }
    for (int k = 32; k < n; k += 8) {
        unsigned off[8];
        #pragma unroll
        for (int i = 0; i < 8; ++i) off[i] = L[k + i];
        float val[8];
        #pragma unroll
        for (int i = 0; i < 8; ++i) val[i] = *(const float*)(mat + (size_t)(off[i] + h4));
        #pragma unroll
        for (int i = 0; i < 8; ++i) acc += (k + i < n) ? val[i] : 0.0f;
    }
    return acc;
}

__global__ __launch_bounds__(1024) void coesn_sim(
    const float* __restrict__ x,        // (B, L, 1)
    const float* __restrict__ x2h,      // (1, H)
    const float* __restrict__ h2h,      // (H, H)
    const float* __restrict__ bias,     // (H)
    const float* __restrict__ lif2hrf,  // (H, H)
    const float* __restrict__ gamma_,   // (H)
    const float* __restrict__ eps_,     // (H)
    float* __restrict__ out,            // (B, 3H) features
    unsigned int* __restrict__ ws)      // (B, 2) spike counts
{
    const int b    = blockIdx.x;
    const int h    = threadIdx.x;
    const int wv   = h >> 6;
    const int lane = h & 63;
    const int wvs  = __builtin_amdgcn_readfirstlane(wv);
    const unsigned h4 = (unsigned)(h * 4);

    __shared__ unsigned int Ls[LISTCAP];  // HRF spike row byte-offsets
    __shared__ unsigned int Ll[LISTCAP];  // LIF spike row byte-offsets
    __shared__ int Cs[16], Cl[16];
    __shared__ unsigned int red[16];

    Ls[h] = 0; Ll[h] = 0;                 // stale entries stay in-range forever
    if (h < LISTCAP - 1024) { Ls[1024 + h] = 0; Ll[1024 + h] = 0; }
    if (h < 16) { Cs[h] = 0; Cl[h] = 0; }

    float hy = 0.f, hz = 0.f, v = 0.f, rp = 0.f;
    float hysum = 0.f, hysq = 0.f;
    unsigned int chrf = 0, clif = 0;

    const float g    = gamma_[h];
    const float e    = eps_[h];
    const float bi   = bias[h];
    const float win  = x2h[h];
    const float ref_decay = expf((float)(-0.042 / 0.25));
    const float* xb  = x + (size_t)b * LSTEPS;

    const char* hmat = (const char*)h2h;
    const char* lmat = (const char*)lif2hrf;

    const unsigned long long below = (1ULL << lane) - 1ULL;

    int ns = 0;   // HRF list length (phase A bound); 0 at t=0

    __syncthreads();

    for (int t = 0; t < LSTEPS; ++t) {
        // ---- phase A: cur = x*x2h + bias + sum of spiking h2h rows ----
        const float xv = xb[t];
        const float cur = gather_rows(xv * win + bi, hmat, h4, Ls, ns);

        // ---- phase B: LIF update + spike + list build ----
        v = v + DTC * (-v / TAUM + cur);
        const float lsp = (v > THETA) ? 1.f : 0.f;
        v -= lsp * THETA;
        clif += (unsigned)lsp;
        const unsigned long long balL = __ballot(lsp > 0.5f);
        if (lane == 0) Cl[wv] = (int)__popcll(balL);
        __syncthreads();
        int cv = Cl[lane & 15];
        int pre = 0, nl = 0;
        #pragma unroll
        for (int i = 0; i < 16; ++i) {
            const int ci = __builtin_amdgcn_readlane(cv, i);
            nl += ci;
            pre += (i < wvs) ? ci : 0;
        }
        if (lsp > 0.5f) Ll[pre + (int)__popcll(balL & below)] = (unsigned)(h * 4096);
        __syncthreads();

        // ---- phase C: drive = sum of spiking lif2hrf rows ----
        const float dr = gather_rows(0.0f, lmat, h4, Ll, nl);

        // ---- phase D: HRF update + spike + stats + list build ----
        hz = hz + DTC * (dr - g * hy - e * hz);
        hy = hy + DTC * hz;
        const float sn = ((hy - THETA - rp) > 0.f) ? 1.f : 0.f;
        rp = rp * ref_decay + sn;
        hysum += hy;
        hysq  += hy * hy;
        chrf += (unsigned)sn;
        const unsigned long long balS = __ballot(sn > 0.5f);
        if (lane == 0) Cs[wv] = (int)__popcll(balS);
        __syncthreads();
        cv = Cs[lane & 15];
        pre = 0; ns = 0;
        #pragma unroll
        for (int i = 0; i < 16; ++i) {
            const int ci = __builtin_amdgcn_readlane(cv, i);
            ns += ci;
            pre += (i < wvs) ? ci : 0;
        }
        if (sn > 0.5f) Ls[pre + (int)__popcll(balS & below)] = (unsigned)(h * 4096);
        __syncthreads();
    }

    // ---- epilogue: features ----
    const float Lf   = (float)LSTEPS;
    const float mean = hysum / Lf;
    const float rms  = sqrtf(hysq / Lf + 1e-8f);
    float var = hysq / Lf - mean * mean;
    var = fmaxf(var, 1e-8f);
    float* ob = out + (size_t)b * (3 * NHID);
    ob[h]            = rms;
    ob[NHID + h]     = sqrtf(var);
    ob[2 * NHID + h] = hy;

    // ---- spike-count reduction (exact ints) ----
    unsigned int c = chrf;
    for (int off = 32; off > 0; off >>= 1) c += __shfl_down(c, off, 64);
    if (lane == 0) red[wv] = c;
    __syncthreads();
    if (h == 0) {
        unsigned int tot = 0;
        for (int i = 0; i < 16; ++i) tot += red[i];
        ws[b * 2] = tot;
    }
    __syncthreads();
    c = clif;
    for (int off = 32; off > 0; off >>= 1) c += __shfl_down(c, off, 64);
    if (lane == 0) red[wv] = c;
    __syncthreads();
    if (h == 0) {
        unsigned int tot = 0;
        for (int i = 0; i < 16; ++i) tot += red[i];
        ws[b * 2 + 1] = tot;
    }
}

__global__ void coesn_final(const unsigned int* __restrict__ ws,
                            float* __restrict__ out)
{
    if (threadIdx.x == 0 && blockIdx.x == 0) {
        unsigned long long hrf = 0, lif = 0;
        for (int b = 0; b < BATCH; ++b) {
            hrf += ws[b * 2];
            lif += ws[b * 2 + 1];
        }
        const float denom = (float)BATCH * (float)LSTEPS * (float)NHID;
        const float r_hrf = (float)hrf / denom;
        const float r_lif = (float)lif / denom;
        float* s = out + (size_t)BATCH * 3 * NHID;
        s[0] = r_hrf;
        s[1] = r_hrf;
        s[2] = r_lif;
    }
}

extern "C" void kernel_launch(void* const* d_in, const int* in_sizes, int n_in,
                              void* d_out, int out_size, void* d_ws, size_t ws_size,
                              hipStream_t stream) {
    const float* x       = (const float*)d_in[0];
    const float* x2h     = (const float*)d_in[1];
    const float* h2h     = (const float*)d_in[2];
    const float* bias    = (const float*)d_in[3];
    const float* lif2hrf = (const float*)d_in[4];
    const float* gamma_  = (const float*)d_in[5];
    const float* eps_    = (const float*)d_in[6];
    float* out = (float*)d_out;
    unsigned int* wsp = (unsigned int*)d_ws;

    coesn_sim<<<BATCH, NHID, 0, stream>>>(x, x2h, h2h, bias, lif2hrf, gamma_, eps_, out, wsp);
    coesn_final<<<1, 64, 0, stream>>>(wsp, out);
}